// Round 6
// baseline (1498.603 us; speedup 1.0000x reference)
//
#include <hip/hip_runtime.h>
#include <hip/hip_bf16.h>
#include <stdint.h>

typedef __bf16 bf16x8 __attribute__((ext_vector_type(8)));
typedef float  f32x4  __attribute__((ext_vector_type(4)));

#define BAR()  asm volatile("s_waitcnt lgkmcnt(0)\n\ts_barrier" ::: "memory")

static __device__ __forceinline__ float sigm(float x) {
  return __builtin_amdgcn_rcpf(1.0f + __builtin_amdgcn_exp2f(x * -1.4426950408889634f));
}
static __device__ __forceinline__ float tanh_fast(float x) {
  // tanh(x) = 1 - 2/(exp2(2x*log2e)+1); saturates correctly via exp2->inf/0
  return 1.0f - 2.0f * __builtin_amdgcn_rcpf(1.0f + __builtin_amdgcn_exp2f(x * 2.8853900817779268f));
}
static __device__ __forceinline__ unsigned short f2bf(float f) {
  return __builtin_bit_cast(unsigned short, (__bf16)f);
}
static __device__ __forceinline__ float bf2f(unsigned short u) {
  union { uint32_t i; float f; } v; v.i = ((uint32_t)u) << 16; return v.f;
}
static __device__ __forceinline__ void async16(const float* g, float* l) {
  __builtin_amdgcn_global_load_lds((__attribute__((address_space(1))) void*)g,
                                   (__attribute__((address_space(3))) void*)l, 16, 0, 0);
}

// Persistent fused kernel: 64 WGs x 512 threads; WG owns 16 batch rows for all
// 512 timesteps. Wave wid owns h-cols wid*16..wid*16+15, gate types i,f,g,o as
// its 4 MFMA N-tiles -> pointwise fully in registers.
// Cross-layer software pipeline: one barrier region computes layer0 gates for
// step t AND layer1 gates for step t-1 (independent: both consume h0(t-1),
// h1(t-2)) -> 1 barrier/step, phases interleave to hide chain latency.
// Weights: whh0 + wih1 + folded W0 in registers (160, AGPR side of the unified
// file); Whh1 in LDS fragment-linear (ds_read_b128 at lane*16, conflict-free).
// x triple-buffer invariant: region t reads x(t) from buf[t%3], prefetches
// x(t+2) into buf[(t+2)%3]; loop starts at t=1 => bufR=1, bufW=0 (round-5 bug
// was bufW=2, which clobbered x(2) issued by the prologue).
__global__ __launch_bounds__(512) __attribute__((amdgpu_waves_per_eu(2, 2)))
void fraud_lstm_kernel(
    const float* __restrict__ x,     const float* __restrict__ Wproj,
    const float* __restrict__ bproj, const float* __restrict__ Wih0,
    const float* __restrict__ Whh0,  const float* __restrict__ bih0,
    const float* __restrict__ bhh0,  const float* __restrict__ Wih1,
    const float* __restrict__ Whh1,  const float* __restrict__ bih1,
    const float* __restrict__ bhh1,  const float* __restrict__ Wh1,
    const float* __restrict__ bh1,   const float* __restrict__ Wh2,
    const float* __restrict__ bh2,   float* __restrict__ out)
{
  // LDS total: 131072 + 8192 + 8192 + 12288 = 159744 B (< 160 KiB)
  __shared__ unsigned short sWf[65536];     // Whh1 frags [wid][n][kk][lane][8] bf16; reused as Wproj stage
  __shared__ unsigned short sH0f[2][2048];  // h0 dbuf, frag-linear [kk][lane][8] bf16
  __shared__ unsigned short sH1f[2][2048];  // h1 dbuf
  __shared__ float sXf[3*1024];             // x tile triple buffer (16 rows x 64 f32), chunk-swizzled

  const int tid  = threadIdx.x;
  const int lane = tid & 63;
  const int wid  = tid >> 6;      // 8 waves
  const int lr   = lane & 15;     // fragment row/col lane index
  const int lg   = lane >> 4;     // k-group
  const int b0   = blockIdx.x * 16;
  const int g0   = wid*16 + lr;   // this lane's h column (gate col within each gate type)

  // ---------------- stage Wproj (f32 [p=64][f=64]) into sWf ----------------
  {
    float* sWp = reinterpret_cast<float*>(sWf);
    for (int i = tid; i < 4096; i += 512) sWp[i] = Wproj[i];
  }
  BAR();

  // ---------------- fold W0[g][f] = sum_p Wih0[g][p]*Wproj[p][f]; fold biases ----------------
  float w0a[2][4][8];
  #pragma unroll
  for (int kk = 0; kk < 2; ++kk)
    #pragma unroll
    for (int n = 0; n < 4; ++n)
      #pragma unroll
      for (int j = 0; j < 8; ++j) w0a[kk][n][j] = 0.f;
  float bacc[4] = {0.f, 0.f, 0.f, 0.f};
  {
    const float* sWp = reinterpret_cast<const float*>(sWf);
    #pragma unroll 2
    for (int p = 0; p < 64; ++p) {
      float av[4];
      #pragma unroll
      for (int n = 0; n < 4; ++n) av[n] = Wih0[(n*128 + g0)*64 + p];
      float bp = bproj[p];
      #pragma unroll
      for (int n = 0; n < 4; ++n) bacc[n] += av[n] * bp;
      #pragma unroll
      for (int kk = 0; kk < 2; ++kk) {
        f32x4 wa = *(const f32x4*)&sWp[p*64 + kk*32 + lg*8];
        f32x4 wb = *(const f32x4*)&sWp[p*64 + kk*32 + lg*8 + 4];
        #pragma unroll
        for (int n = 0; n < 4; ++n)
          #pragma unroll
          for (int j = 0; j < 4; ++j) {
            w0a[kk][n][j]     += av[n] * wa[j];
            w0a[kk][n][4 + j] += av[n] * wb[j];
          }
      }
    }
  }
  bf16x8 w0f[2][4];
  #pragma unroll
  for (int kk = 0; kk < 2; ++kk)
    #pragma unroll
    for (int n = 0; n < 4; ++n)
      #pragma unroll
      for (int j = 0; j < 8; ++j) w0f[kk][n][j] = (__bf16)w0a[kk][n][j];

  float b0r[4], b1r[4];
  #pragma unroll
  for (int n = 0; n < 4; ++n) {
    const int g = n*128 + g0;
    b0r[n] = bih0[g] + bhh0[g] + bacc[n];
    b1r[n] = bih1[g] + bhh1[g];
  }
  BAR();   // everyone done reading the Wproj stage; sWf free for weight frags

  // ---------------- whh0, wih1 -> reg frags; whh1 -> LDS frag-linear ----------------
  bf16x8 whh0[4][4], wih1[4][4];
  #pragma unroll
  for (int n = 0; n < 4; ++n)
    #pragma unroll
    for (int kk = 0; kk < 4; ++kk) {
      const int ro = (n*128 + g0)*128 + kk*32 + lg*8;
      const float* p0 = Whh0 + ro;
      const float* p1 = Wih1 + ro;
      #pragma unroll
      for (int j = 0; j < 8; ++j) {
        whh0[n][kk][j] = (__bf16)p0[j];
        wih1[n][kk][j] = (__bf16)p1[j];
      }
    }
  #pragma unroll
  for (int n = 0; n < 4; ++n)
    #pragma unroll
    for (int kk = 0; kk < 4; ++kk) {
      const int ro = (n*128 + g0)*128 + kk*32 + lg*8;
      const float* p2 = Whh1 + ro;
      bf16x8 w;
      #pragma unroll
      for (int j = 0; j < 8; ++j) w[j] = (__bf16)p2[j];
      *(bf16x8*)&sWf[((wid*16 + n*4 + kk)*64 + lane)*8] = w;
    }

  // zero h buffers
  for (int i = tid; i < 2048; i += 512) {
    sH0f[0][i] = 0; sH0f[1][i] = 0; sH1f[0][i] = 0; sH1f[1][i] = 0;
  }

  // ---------------- x prefetch (pre-swizzled global source -> linear LDS) ----------------
  const int schunk = (wid & 3)*64 + lane;          // 256 16B-chunks per tile
  const int xrow   = schunk >> 4;                  // 0..15
  const int xcc    = (schunk & 15) ^ (xrow & 7);   // swizzled source column chunk
  const float* xg  = x + ((size_t)(b0 + xrow) * 512) * 64 + xcc*4;  // t = 0
  if (wid < 4) {
    async16(xg, &sXf[0*1024 + wid*256]); xg += 64;   // t=0
    async16(xg, &sXf[1*1024 + wid*256]); xg += 64;   // t=1
    asm volatile("s_waitcnt vmcnt(1)" ::: "memory"); // t=0 landed
  }
  BAR();   // weight frags in LDS + h zeroed + x(0) visible

  // fragment-read chunk offsets within an x buffer (conflict-free after swizzle)
  const int xo00 = lr*16 + ((lg*2 + 0) ^ (lr & 7));
  const int xo01 = lr*16 + ((lg*2 + 1) ^ (lr & 7));
  const int xo10 = lr*16 + ((8 + lg*2 + 0) ^ (lr & 7));
  const int xo11 = lr*16 + ((8 + lg*2 + 1) ^ (lr & 7));

  // h write base for this lane's column (frag-linear): kk*512 + lgk*128 + row*8 + j
  const int hbase = (g0 >> 5)*512 + ((g0 >> 3) & 3)*128 + (g0 & 7);

  f32x4 c0r = {0.f,0.f,0.f,0.f}, c1r = {0.f,0.f,0.f,0.f};

  // ================ prologue region: A(0) only ================
  {
    if (wid < 4) { async16(xg, &sXf[2*1024 + wid*256]); xg += 64; }   // x(2) -> buf2
    f32x4 acc0[4];
    #pragma unroll
    for (int n = 0; n < 4; ++n) acc0[n] = f32x4{b0r[n], b0r[n], b0r[n], b0r[n]};
    const f32x4* xb = (const f32x4*)&sXf[0];
    #pragma unroll
    for (int kk = 0; kk < 2; ++kk) {
      f32x4 a0 = xb[kk ? xo10 : xo00];
      f32x4 a1 = xb[kk ? xo11 : xo01];
      bf16x8 xa;
      #pragma unroll
      for (int j = 0; j < 4; ++j) { xa[j] = (__bf16)a0[j]; xa[4+j] = (__bf16)a1[j]; }
      #pragma unroll
      for (int n = 0; n < 4; ++n)
        acc0[n] = __builtin_amdgcn_mfma_f32_16x16x32_bf16(xa, w0f[kk][n], acc0[n], 0, 0, 0);
    }
    // h0(-1) == 0 -> skip Whh0 MFMAs
    #pragma unroll
    for (int r = 0; r < 4; ++r) {
      float iv = sigm(acc0[0][r]);
      float fv = sigm(acc0[1][r]);
      float gv = tanh_fast(acc0[2][r]);
      float ov = sigm(acc0[3][r]);
      float c  = fv * c0r[r] + iv * gv;
      c0r[r] = c;
      sH0f[0][hbase + (lg*4 + r)*8] = f2bf(ov * tanh_fast(c));
    }
    if (wid < 4) asm volatile("s_waitcnt vmcnt(1)" ::: "memory");  // x(1) landed
    BAR();
  }
  // region t reads x(t) from buf[t%3], prefetches x(t+2) into buf[(t+2)%3]
  int bufR = 1, bufW = 0;   // t=1: read x(1)<-buf1, write x(3)->buf0

  // ================ main loop: region t computes A(t) + B(t-1), 1 barrier ================
  #pragma unroll 1
  for (int t = 1; t < 512; ++t) {
    const int cur = t & 1;

    // prefetch x(t+2)
    if (wid < 4 && t < 510) { async16(xg, &sXf[bufW*1024 + wid*256]); xg += 64; }

    f32x4 acc0[4], acc1[4];
    #pragma unroll
    for (int n = 0; n < 4; ++n) {
      acc0[n] = f32x4{b0r[n], b0r[n], b0r[n], b0r[n]};
      acc1[n] = f32x4{b1r[n], b1r[n], b1r[n], b1r[n]};
    }

    // ---- A(t): x(t) @ W0^T ----
    const f32x4* xb = (const f32x4*)&sXf[bufR*1024];
    #pragma unroll
    for (int kk = 0; kk < 2; ++kk) {
      f32x4 a0 = xb[kk ? xo10 : xo00];
      f32x4 a1 = xb[kk ? xo11 : xo01];
      bf16x8 xa;
      #pragma unroll
      for (int j = 0; j < 4; ++j) { xa[j] = (__bf16)a0[j]; xa[4+j] = (__bf16)a1[j]; }
      #pragma unroll
      for (int n = 0; n < 4; ++n)
        acc0[n] = __builtin_amdgcn_mfma_f32_16x16x32_bf16(xa, w0f[kk][n], acc0[n], 0, 0, 0);
    }

    // ---- shared h0(t-1) fragments feed A's Whh0 and B's Wih1 ----
    #pragma unroll
    for (int kk = 0; kk < 4; ++kk) {
      bf16x8 ha = *(const bf16x8*)&sH0f[cur ^ 1][(kk*64 + lane)*8];
      #pragma unroll
      for (int n = 0; n < 4; ++n) {
        acc0[n] = __builtin_amdgcn_mfma_f32_16x16x32_bf16(ha, whh0[n][kk], acc0[n], 0, 0, 0);
        acc1[n] = __builtin_amdgcn_mfma_f32_16x16x32_bf16(ha, wih1[n][kk], acc1[n], 0, 0, 0);
      }
    }

    // ---- B(t-1): h1(t-2) @ Whh1^T (weights from LDS) ----
    #pragma unroll
    for (int kk = 0; kk < 4; ++kk) {
      bf16x8 ha = *(const bf16x8*)&sH1f[cur][(kk*64 + lane)*8];
      #pragma unroll
      for (int n = 0; n < 4; ++n) {
        bf16x8 wf = *(const bf16x8*)&sWf[((wid*16 + n*4 + kk)*64 + lane)*8];
        acc1[n] = __builtin_amdgcn_mfma_f32_16x16x32_bf16(ha, wf, acc1[n], 0, 0, 0);
      }
    }

    // ---- pointwise layer 0 -> h0(t) ----
    #pragma unroll
    for (int r = 0; r < 4; ++r) {
      float iv = sigm(acc0[0][r]);
      float fv = sigm(acc0[1][r]);
      float gv = tanh_fast(acc0[2][r]);
      float ov = sigm(acc0[3][r]);
      float c  = fv * c0r[r] + iv * gv;
      c0r[r] = c;
      sH0f[cur][hbase + (lg*4 + r)*8] = f2bf(ov * tanh_fast(c));
    }
    // ---- pointwise layer 1 -> h1(t-1) ----
    #pragma unroll
    for (int r = 0; r < 4; ++r) {
      float iv = sigm(acc1[0][r]);
      float fv = sigm(acc1[1][r]);
      float gv = tanh_fast(acc1[2][r]);
      float ov = sigm(acc1[3][r]);
      float c  = fv * c1r[r] + iv * gv;
      c1r[r] = c;
      sH1f[cur ^ 1][hbase + (lg*4 + r)*8] = f2bf(ov * tanh_fast(c));
    }

    // drain x prefetch: x(t+1) must be landed before next region
    if (wid < 4) {
      if (t < 510) asm volatile("s_waitcnt vmcnt(1)" ::: "memory");
      else         asm volatile("s_waitcnt vmcnt(0)" ::: "memory");
    }
    BAR();   // h0(t), h1(t-1), x(t+1) visible

    bufR = (bufR == 2) ? 0 : bufR + 1;
    bufW = (bufW == 2) ? 0 : bufW + 1;
  }

  // ================ epilogue: B(511) ================
  {
    f32x4 acc1[4];
    #pragma unroll
    for (int n = 0; n < 4; ++n) acc1[n] = f32x4{b1r[n], b1r[n], b1r[n], b1r[n]};
    #pragma unroll
    for (int kk = 0; kk < 4; ++kk) {
      bf16x8 ha = *(const bf16x8*)&sH0f[1][(kk*64 + lane)*8];   // h0(511)
      #pragma unroll
      for (int n = 0; n < 4; ++n)
        acc1[n] = __builtin_amdgcn_mfma_f32_16x16x32_bf16(ha, wih1[n][kk], acc1[n], 0, 0, 0);
    }
    #pragma unroll
    for (int kk = 0; kk < 4; ++kk) {
      bf16x8 ha = *(const bf16x8*)&sH1f[0][(kk*64 + lane)*8];   // h1(510)
      #pragma unroll
      for (int n = 0; n < 4; ++n) {
        bf16x8 wf = *(const bf16x8*)&sWf[((wid*16 + n*4 + kk)*64 + lane)*8];
        acc1[n] = __builtin_amdgcn_mfma_f32_16x16x32_bf16(ha, wf, acc1[n], 0, 0, 0);
      }
    }
    #pragma unroll
    for (int r = 0; r < 4; ++r) {
      float iv = sigm(acc1[0][r]);
      float fv = sigm(acc1[1][r]);
      float gv = tanh_fast(acc1[2][r]);
      float ov = sigm(acc1[3][r]);
      float c  = fv * c1r[r] + iv * gv;
      c1r[r] = c;
      sH1f[1][hbase + (lg*4 + r)*8] = f2bf(ov * tanh_fast(c));  // h1(511)
    }
    BAR();
  }

  // ---------------- head: hid = relu(h1 @ Wh1^T + bh1); out = hid @ Wh2^T + bh2 ----------------
  // final h1(511) is in sH1f[1]. Reuse sXf as f32 scratch [16][64].
  {
    int row = tid >> 5;          // 0..15
    int j0  = (tid & 31) * 2;    // 0..62
    float a0 = bh1[j0], a1 = bh1[j0 + 1];
    const float* w0 = Wh1 + j0*128;
    const float* w1 = w0 + 128;
    #pragma unroll 8
    for (int k = 0; k < 128; ++k) {
      float hv = bf2f(sH1f[1][(k >> 5)*512 + ((k >> 3) & 3)*128 + row*8 + (k & 7)]);
      a0 += hv * w0[k];
      a1 += hv * w1[k];
    }
    sXf[row*64 + j0]     = fmaxf(a0, 0.f);
    sXf[row*64 + j0 + 1] = fmaxf(a1, 0.f);
  }
  BAR();
  if (tid < 16) {
    float a = bh2[0];
    #pragma unroll 8
    for (int j = 0; j < 64; ++j) a += sXf[tid*64 + j] * Wh2[j];
    out[b0 + tid] = a;
  }
}

extern "C" void kernel_launch(void* const* d_in, const int* in_sizes, int n_in,
                              void* d_out, int out_size, void* d_ws, size_t ws_size,
                              hipStream_t stream) {
  (void)in_sizes; (void)n_in; (void)d_ws; (void)ws_size; (void)out_size;
  const float* x     = (const float*)d_in[0];
  // d_in[1] = lengths (unused by reference)
  const float* Wproj = (const float*)d_in[2];
  const float* bproj = (const float*)d_in[3];
  const float* Wih0  = (const float*)d_in[4];
  const float* Whh0  = (const float*)d_in[5];
  const float* bih0  = (const float*)d_in[6];
  const float* bhh0  = (const float*)d_in[7];
  const float* Wih1  = (const float*)d_in[8];
  const float* Whh1  = (const float*)d_in[9];
  const float* bih1  = (const float*)d_in[10];
  const float* bhh1  = (const float*)d_in[11];
  const float* Wh1   = (const float*)d_in[12];
  const float* bh1   = (const float*)d_in[13];
  const float* Wh2   = (const float*)d_in[14];
  const float* bh2   = (const float*)d_in[15];
  float* out = (float*)d_out;

  hipLaunchKernelGGL(fraud_lstm_kernel, dim3(64), dim3(512), 0, stream,
                     x, Wproj, bproj, Wih0, Whh0, bih0, bhh0,
                     Wih1, Whh1, bih1, bhh1, Wh1, bh1, Wh2, bh2, out);
}

// Round 7
// 1125.870 us; speedup vs baseline: 1.3311x; 1.3311x over previous
//
#include <hip/hip_runtime.h>
#include <hip/hip_bf16.h>
#include <stdint.h>

typedef __bf16 bf16x8 __attribute__((ext_vector_type(8)));
typedef float  f32x4  __attribute__((ext_vector_type(4)));

#define BAR()  asm volatile("s_waitcnt lgkmcnt(0)\n\ts_barrier" ::: "memory")
#define SB()   __builtin_amdgcn_sched_barrier(0)

static __device__ __forceinline__ float sigm(float x) {
  return __builtin_amdgcn_rcpf(1.0f + __builtin_amdgcn_exp2f(x * -1.4426950408889634f));
}
static __device__ __forceinline__ float tanh_fast(float x) {
  return 1.0f - 2.0f * __builtin_amdgcn_rcpf(1.0f + __builtin_amdgcn_exp2f(x * 2.8853900817779268f));
}
static __device__ __forceinline__ unsigned short f2bf(float f) {
  return __builtin_bit_cast(unsigned short, (__bf16)f);
}
static __device__ __forceinline__ float bf2f(unsigned short u) {
  union { uint32_t i; float f; } v; v.i = ((uint32_t)u) << 16; return v.f;
}
static __device__ __forceinline__ void async16(const float* g, float* l) {
  __builtin_amdgcn_global_load_lds((__attribute__((address_space(1))) void*)g,
                                   (__attribute__((address_space(3))) void*)l, 16, 0, 0);
}

// 64 WGs x 512 threads persistent. Wave wid owns h-cols wid*16..+15, gate types
// i,f,g,o as its 4 MFMA N-tiles; pointwise in registers.
// One barrier/step: region t = A(t) (layer0, consumes h0(t-1)) + B(t-1)
// (layer1, consumes h0(t-1), h1(t-2)). sched_barrier(0) fences per kk-cluster
// cap scheduler hoisting (register live-range control); acc0 dies at pw0
// before acc1 is born.
__global__ __launch_bounds__(512) __attribute__((amdgpu_waves_per_eu(2, 2)))
void fraud_lstm_kernel(
    const float* __restrict__ x,     const float* __restrict__ Wproj,
    const float* __restrict__ bproj, const float* __restrict__ Wih0,
    const float* __restrict__ Whh0,  const float* __restrict__ bih0,
    const float* __restrict__ bhh0,  const float* __restrict__ Wih1,
    const float* __restrict__ Whh1,  const float* __restrict__ bih1,
    const float* __restrict__ bhh1,  const float* __restrict__ Wh1,
    const float* __restrict__ bh1,   const float* __restrict__ Wh2,
    const float* __restrict__ bh2,   float* __restrict__ out)
{
  // LDS: 131072 + 8192 + 8192 + 12288 = 159744 B
  __shared__ unsigned short sWf[65536];     // Whh1 frags [wid][n*4+kk][lane][8]; also Wproj stage
  __shared__ unsigned short sH0f[2][2048];  // h0 dbuf, frag-linear [kk][lane][8]
  __shared__ unsigned short sH1f[2][2048];  // h1 dbuf
  __shared__ float sXB[3*1024];             // x triple buffer, frag-linear [kk][half][lane][4]

  const int tid  = threadIdx.x;
  const int lane = tid & 63;
  const int wid  = tid >> 6;
  const int lr   = lane & 15;
  const int lg   = lane >> 4;
  const int b0   = blockIdx.x * 16;
  const int g0   = wid*16 + lr;

  // ---------------- stage Wproj (f32 [64][64]) into sWf ----------------
  {
    float* sWp = reinterpret_cast<float*>(sWf);
    for (int i = tid; i < 4096; i += 512) sWp[i] = Wproj[i];
  }
  BAR();

  // ---------------- fold W0 = Wih0 @ Wproj (per-lane f32); fold biases ----------------
  float w0a[2][4][8];
  #pragma unroll
  for (int kk = 0; kk < 2; ++kk)
    #pragma unroll
    for (int n = 0; n < 4; ++n)
      #pragma unroll
      for (int j = 0; j < 8; ++j) w0a[kk][n][j] = 0.f;
  float bacc[4] = {0.f, 0.f, 0.f, 0.f};
  {
    const float* sWp = reinterpret_cast<const float*>(sWf);
    #pragma unroll 2
    for (int p = 0; p < 64; ++p) {
      float av[4];
      #pragma unroll
      for (int n = 0; n < 4; ++n) av[n] = Wih0[(n*128 + g0)*64 + p];
      float bp = bproj[p];
      #pragma unroll
      for (int n = 0; n < 4; ++n) bacc[n] += av[n] * bp;
      #pragma unroll
      for (int kk = 0; kk < 2; ++kk) {
        f32x4 wa = *(const f32x4*)&sWp[p*64 + kk*32 + lg*8];
        f32x4 wb = *(const f32x4*)&sWp[p*64 + kk*32 + lg*8 + 4];
        #pragma unroll
        for (int n = 0; n < 4; ++n)
          #pragma unroll
          for (int j = 0; j < 4; ++j) {
            w0a[kk][n][j]     += av[n] * wa[j];
            w0a[kk][n][4 + j] += av[n] * wb[j];
          }
      }
    }
  }
  bf16x8 w0f[2][4];
  #pragma unroll
  for (int kk = 0; kk < 2; ++kk)
    #pragma unroll
    for (int n = 0; n < 4; ++n)
      #pragma unroll
      for (int j = 0; j < 8; ++j) w0f[kk][n][j] = (__bf16)w0a[kk][n][j];

  float b0r[4], b1r[4];
  #pragma unroll
  for (int n = 0; n < 4; ++n) {
    const int g = n*128 + g0;
    b0r[n] = bih0[g] + bhh0[g] + bacc[n];
    b1r[n] = bih1[g] + bhh1[g];
  }
  BAR();   // Wproj stage dead; sWf free

  // ---------------- whh0, wih1 -> regs; Whh1 -> LDS frag-linear ----------------
  bf16x8 whh0[4][4], wih1[4][4];
  #pragma unroll
  for (int n = 0; n < 4; ++n)
    #pragma unroll
    for (int kk = 0; kk < 4; ++kk) {
      const int ro = (n*128 + g0)*128 + kk*32 + lg*8;
      const float* p0 = Whh0 + ro;
      const float* p1 = Wih1 + ro;
      #pragma unroll
      for (int j = 0; j < 8; ++j) {
        whh0[n][kk][j] = (__bf16)p0[j];
        wih1[n][kk][j] = (__bf16)p1[j];
      }
    }
  #pragma unroll
  for (int n = 0; n < 4; ++n)
    #pragma unroll
    for (int kk = 0; kk < 4; ++kk) {
      const int ro = (n*128 + g0)*128 + kk*32 + lg*8;
      const float* p2 = Whh1 + ro;
      bf16x8 w;
      #pragma unroll
      for (int j = 0; j < 8; ++j) w[j] = (__bf16)p2[j];
      *(bf16x8*)&sWf[((wid*16 + n*4 + kk)*64 + lane)*8] = w;
    }

  for (int i = tid; i < 2048; i += 512) {
    sH0f[0][i] = 0; sH0f[1][i] = 0; sH1f[0][i] = 0; sH1f[1][i] = 0;
  }

  // ---------------- x staging: frag-linear, per-lane permuted global source ----------------
  // region w (=wid<4): kk=w>>1, half=w&1. lane l supplies x[b0+(l&15)][t][kk*32+(l>>4)*8+(w&1)*4 ..+3]
  const float* xw = x + (size_t)(b0 + (lane & 15)) * (512*64)
                      + ((wid >> 1) & 1) * 32 + (lane >> 4) * 8 + (wid & 1) * 4;
  if (wid < 4) {
    async16(xw,      &sXB[0*1024 + wid*256]);   // x(0) -> buf0
    async16(xw + 64, &sXB[1*1024 + wid*256]);   // x(1) -> buf1
    asm volatile("s_waitcnt vmcnt(1)" ::: "memory");
  }
  BAR();

  // h write base (bytes): h[col g0] -> frag kk=g0>>5, lane ((g0>>3)&3)*16+row, short j=g0&7
  const int hwb = (g0 >> 5)*1024 + ((g0 >> 3) & 3)*256 + (g0 & 7)*2 + lg*64;
  const int lb  = lane * 16;

  f32x4 c0r = {0.f,0.f,0.f,0.f}, c1r = {0.f,0.f,0.f,0.f};
  int bufR = 0, bufW = 2;

  // ================ main loop: region t = A(t) + B(t-1), one barrier ================
  #pragma unroll 1
  for (int t = 0; t < 512; ++t) {
    const int cur = t & 1;

    if (wid < 4 && t < 510) async16(xw + (t + 2)*64, &sXB[bufW*1024 + wid*256]);

    // ---- A(t): x(t)@W0^T ----
    f32x4 acc0[4];
    #pragma unroll
    for (int n = 0; n < 4; ++n) acc0[n] = f32x4{b0r[n], b0r[n], b0r[n], b0r[n]};
    const char* xp = (const char*)sXB + bufR*4096 + lb;
    #pragma unroll
    for (int kk = 0; kk < 2; ++kk) {
      f32x4 a0 = *(const f32x4*)(xp + kk*2048);
      f32x4 a1 = *(const f32x4*)(xp + kk*2048 + 1024);
      bf16x8 xa;
      #pragma unroll
      for (int j = 0; j < 4; ++j) { xa[j] = (__bf16)a0[j]; xa[4+j] = (__bf16)a1[j]; }
      #pragma unroll
      for (int n = 0; n < 4; ++n)
        acc0[n] = __builtin_amdgcn_mfma_f32_16x16x32_bf16(xa, w0f[kk][n], acc0[n], 0, 0, 0);
      SB();
    }
    // ---- A(t): h0(t-1)@Whh0^T ----
    const char* h0p = (const char*)sH0f[cur ^ 1] + lb;
    #pragma unroll
    for (int kk = 0; kk < 4; ++kk) {
      bf16x8 ha = *(const bf16x8*)(h0p + kk*1024);
      #pragma unroll
      for (int n = 0; n < 4; ++n)
        acc0[n] = __builtin_amdgcn_mfma_f32_16x16x32_bf16(ha, whh0[n][kk], acc0[n], 0, 0, 0);
      SB();
    }
    // ---- pointwise 0 -> h0(t) (acc0 dies here) ----
    {
      char* hw = (char*)sH0f[cur] + hwb;
      #pragma unroll
      for (int r = 0; r < 4; ++r) {
        float iv = sigm(acc0[0][r]);
        float fv = sigm(acc0[1][r]);
        float gv = tanh_fast(acc0[2][r]);
        float ov = sigm(acc0[3][r]);
        float c  = fv * c0r[r] + iv * gv;
        c0r[r] = c;
        *(unsigned short*)(hw + r*16) = f2bf(ov * tanh_fast(c));
      }
    }
    SB();
    // ---- B(t-1): h0(t-1)@Wih1^T ----
    f32x4 acc1[4];
    #pragma unroll
    for (int n = 0; n < 4; ++n) acc1[n] = f32x4{b1r[n], b1r[n], b1r[n], b1r[n]};
    #pragma unroll
    for (int kk = 0; kk < 4; ++kk) {
      bf16x8 ha = *(const bf16x8*)(h0p + kk*1024);
      #pragma unroll
      for (int n = 0; n < 4; ++n)
        acc1[n] = __builtin_amdgcn_mfma_f32_16x16x32_bf16(ha, wih1[n][kk], acc1[n], 0, 0, 0);
      SB();
    }
    // ---- B(t-1): h1(t-2)@Whh1^T (weights from LDS) ----
    const char* h1p = (const char*)sH1f[cur] + lb;
    const char* wp  = (const char*)sWf + wid*16384 + lb;
    #pragma unroll
    for (int kk = 0; kk < 4; ++kk) {
      bf16x8 ha = *(const bf16x8*)(h1p + kk*1024);
      #pragma unroll
      for (int n = 0; n < 4; ++n) {
        bf16x8 wf = *(const bf16x8*)(wp + (n*4 + kk)*1024);
        acc1[n] = __builtin_amdgcn_mfma_f32_16x16x32_bf16(ha, wf, acc1[n], 0, 0, 0);
      }
      SB();
    }
    // ---- pointwise 1 -> h1(t-1); skipped at t=0 (h1(-1) must stay 0) ----
    if (t > 0) {
      char* hw = (char*)sH1f[cur ^ 1] + hwb;
      #pragma unroll
      for (int r = 0; r < 4; ++r) {
        float iv = sigm(acc1[0][r]);
        float fv = sigm(acc1[1][r]);
        float gv = tanh_fast(acc1[2][r]);
        float ov = sigm(acc1[3][r]);
        float c  = fv * c1r[r] + iv * gv;
        c1r[r] = c;
        *(unsigned short*)(hw + r*16) = f2bf(ov * tanh_fast(c));
      }
    }

    if (wid < 4) {
      if (t < 510) asm volatile("s_waitcnt vmcnt(1)" ::: "memory");
      else         asm volatile("s_waitcnt vmcnt(0)" ::: "memory");
    }
    BAR();   // h0(t), h1(t-1), x(t+1) visible

    bufR = (bufR == 2) ? 0 : bufR + 1;
    bufW = (bufW == 2) ? 0 : bufW + 1;
  }

  // ================ epilogue: B(511) ================
  {
    f32x4 acc1[4];
    #pragma unroll
    for (int n = 0; n < 4; ++n) acc1[n] = f32x4{b1r[n], b1r[n], b1r[n], b1r[n]};
    const char* h0p = (const char*)sH0f[1] + lb;   // h0(511)
    #pragma unroll
    for (int kk = 0; kk < 4; ++kk) {
      bf16x8 ha = *(const bf16x8*)(h0p + kk*1024);
      #pragma unroll
      for (int n = 0; n < 4; ++n)
        acc1[n] = __builtin_amdgcn_mfma_f32_16x16x32_bf16(ha, wih1[n][kk], acc1[n], 0, 0, 0);
    }
    const char* h1p = (const char*)sH1f[0] + lb;   // h1(510)
    const char* wp  = (const char*)sWf + wid*16384 + lb;
    #pragma unroll
    for (int kk = 0; kk < 4; ++kk) {
      bf16x8 ha = *(const bf16x8*)(h1p + kk*1024);
      #pragma unroll
      for (int n = 0; n < 4; ++n) {
        bf16x8 wf = *(const bf16x8*)(wp + (n*4 + kk)*1024);
        acc1[n] = __builtin_amdgcn_mfma_f32_16x16x32_bf16(ha, wf, acc1[n], 0, 0, 0);
      }
    }
    char* hw = (char*)sH1f[1] + hwb;               // h1(511)
    #pragma unroll
    for (int r = 0; r < 4; ++r) {
      float iv = sigm(acc1[0][r]);
      float fv = sigm(acc1[1][r]);
      float gv = tanh_fast(acc1[2][r]);
      float ov = sigm(acc1[3][r]);
      float c  = fv * c1r[r] + iv * gv;
      c1r[r] = c;
      *(unsigned short*)(hw + r*16) = f2bf(ov * tanh_fast(c));
    }
    BAR();
  }

  // ---------------- head: hid = relu(h1@Wh1^T + bh1); out = hid@Wh2^T + bh2 ----------------
  {
    int row = tid >> 5;
    int j0  = (tid & 31) * 2;
    float a0 = bh1[j0], a1 = bh1[j0 + 1];
    const float* w0 = Wh1 + j0*128;
    const float* w1 = w0 + 128;
    #pragma unroll 8
    for (int k = 0; k < 128; ++k) {
      float hv = bf2f(sH1f[1][(k >> 5)*512 + ((k >> 3) & 3)*128 + row*8 + (k & 7)]);
      a0 += hv * w0[k];
      a1 += hv * w1[k];
    }
    sXB[row*64 + j0]     = fmaxf(a0, 0.f);
    sXB[row*64 + j0 + 1] = fmaxf(a1, 0.f);
  }
  BAR();
  if (tid < 16) {
    float a = bh2[0];
    #pragma unroll 8
    for (int j = 0; j < 64; ++j) a += sXB[tid*64 + j] * Wh2[j];
    out[b0 + tid] = a;
  }
}

extern "C" void kernel_launch(void* const* d_in, const int* in_sizes, int n_in,
                              void* d_out, int out_size, void* d_ws, size_t ws_size,
                              hipStream_t stream) {
  (void)in_sizes; (void)n_in; (void)d_ws; (void)ws_size; (void)out_size;
  const float* x     = (const float*)d_in[0];
  const float* Wproj = (const float*)d_in[2];
  const float* bproj = (const float*)d_in[3];
  const float* Wih0  = (const float*)d_in[4];
  const float* Whh0  = (const float*)d_in[5];
  const float* bih0  = (const float*)d_in[6];
  const float* bhh0  = (const float*)d_in[7];
  const float* Wih1  = (const float*)d_in[8];
  const float* Whh1  = (const float*)d_in[9];
  const float* bih1  = (const float*)d_in[10];
  const float* bhh1  = (const float*)d_in[11];
  const float* Wh1   = (const float*)d_in[12];
  const float* bh1   = (const float*)d_in[13];
  const float* Wh2   = (const float*)d_in[14];
  const float* bh2   = (const float*)d_in[15];
  float* out = (float*)d_out;

  hipLaunchKernelGGL(fraud_lstm_kernel, dim3(64), dim3(512), 0, stream,
                     x, Wproj, bproj, Wih0, Whh0, bih0, bhh0,
                     Wih1, Whh1, bih1, bhh1, Wh1, bh1, Wh2, bh2, out);
}